// Round 6
// baseline (374.176 us; speedup 1.0000x reference)
//
#include <hip/hip_runtime.h>
#include <hip/hip_bf16.h>

typedef __attribute__((ext_vector_type(8))) short s16x8;
typedef __attribute__((ext_vector_type(4))) float f32x4;

#define WS_SEG 67108864ULL  // 64 MiB regions: [O][Q][K][Vt]

#if defined(__has_attribute)
#if __has_attribute(amdgpu_num_vgpr)
#define VGPR_CAP_128 __attribute__((amdgpu_num_vgpr(128)))
#else
#define VGPR_CAP_128
#endif
#else
#define VGPR_CAP_128
#endif

static __device__ __forceinline__ unsigned short f2bf(float f) {
    return __builtin_bit_cast(unsigned short, __float2bfloat16(f));   // RNE v_cvt
}
static __device__ __forceinline__ unsigned int pack2(float a, float b) {
    return (unsigned int)f2bf(a) | ((unsigned int)f2bf(b) << 16);     // v_cvt_pk path
}
static __device__ __forceinline__ s16x8 u4cast(uint4 u) {
    return __builtin_bit_cast(s16x8, u);
}
// async global->LDS, 16B per lane; lds dest = wave-uniform base + lane*16
static __device__ __forceinline__ void gl_lds16(const void* g, void* l) {
    __builtin_amdgcn_global_load_lds(
        (const __attribute__((address_space(1))) unsigned int*)g,
        (__attribute__((address_space(3))) unsigned int*)l, 16, 0, 0);
}

// ---------------------------------------------------------------------------
// Weight convert f32 -> bf16, pre-swizzled: within each 128B k-chunk of a row,
// phys_cb = cb ^ ((row&7)<<4).
// ---------------------------------------------------------------------------
__global__ __launch_bounds__(256) void convw_swz(const float* __restrict__ wi,
                                                 unsigned short* __restrict__ wb) {
    int i = (blockIdx.x * 256 + threadIdx.x) * 4;   // element idx
    float4 v = *reinterpret_cast<const float4*>(wi + i);
    int bb = i * 2;                                  // byte addr in bf16 matrix
    int row = i >> 8;
    int dst = (bb & ~127) | ((bb & 127) ^ ((row & 7) << 4));
    uint2 o = { pack2(v.x, v.y), pack2(v.z, v.w) };
    *reinterpret_cast<uint2*>((char*)wb + dst) = o;
}

// ---------------------------------------------------------------------------
// GEMM with fused A-source and 2-phase pipeline.
//   C[M=131072][N] = A @ W^T + bias, K=256, tile 128x128, BK=64, 4 waves.
// A-staging: registers -> LDS (single 16KB buffer, swizzled).
//   MODE 0: A gathered DIRECTLY from x (f32, patch layout) with on-the-fly
//           bf16 convert — the standalone gather kernel is gone.
//   MODE 1: A = attn O (bf16, pre-swizzled rows of 512B) straight copy.
// B-staging: gl_lds16 into double-buffered 2x16KB (phys copy, pre-swizzled W).
// Pipeline per K-tile: writeA -> barrier -> issue loads(kk+1) -> compute(kk)
//                      -> barrier. Loads fly during compute.
// 1-D grid, XCD-chunked: NB consecutive bn per bm -> A/x re-reads are L2-hits.
// MODE 0 epilogue: LDS transpose -> Q/K [nh][c][64], Vt [nh][64][c].
// MODE 1 epilogue: direct f32 stores to out [b][c][p][e].
// ---------------------------------------------------------------------------
template<int MODE>
__global__ __launch_bounds__(256) void gemm4(
    const float* __restrict__ Xf,            // MODE 0 A-source
    const unsigned short* __restrict__ Ab,   // MODE 1 A-source
    const unsigned short* __restrict__ Wb,
    const float* __restrict__ bias,
    unsigned short* __restrict__ Qo, unsigned short* __restrict__ Ko,
    unsigned short* __restrict__ Vt, float* __restrict__ Out)
{
    __shared__ __align__(16) char smem[49152];   // As 16K | Bs[0] 16K | Bs[1] 16K
    char* AsB = smem;
    char* BsB0 = smem + 16384;

    const int t = threadIdx.x, w = t >> 6, lane = t & 63;
    const int lr = lane & 15, lk = lane >> 4;
    const int wm = w >> 1, wn = w & 1;

    constexpr int NB = (MODE == 0) ? 6 : 2;
    const int flat = blockIdx.x;
    const int xcd = flat & 7, idx = flat >> 3;
    const int bm = xcd * 128 + idx / NB;
    const int bn = idx % NB;

    // ---- A-source address setup
    const float* xrow = nullptr;
    const char* Arow = nullptr;
    if (MODE == 0) {
        const int r = t >> 1;
        const int n_ = bm >> 1;                       // block-uniform
        const int b_ = n_ >> 8, p_ = n_ & 255;
        const int c_ = (bm & 1) * 128 + r;
        xrow = Xf + (((size_t)(b_ * 256 + c_) * 256 + (p_ >> 4) * 16) * 256
                     + (p_ & 15) * 16);
    } else {
        Arow = (const char*)Ab + (size_t)bm * 65536;  // 128 rows * 512B
    }
    const char* Bg = (const char*)Wb + (size_t)bn * 65536;

    float4 fa[4][2];   // MODE 0 staged A (32 f32)
    uint4  ua[4];      // MODE 1 staged A (64B)

    auto loadA = [&](int kk) {
        if (MODE == 0) {
            #pragma unroll
            for (int s = 0; s < 4; ++s) {
                int eg = kk * 64 + (t & 1) * 32 + s * 8;
                const float* p = xrow + (eg >> 4) * 256 + (eg & 15);
                fa[s][0] = *reinterpret_cast<const float4*>(p);
                fa[s][1] = *reinterpret_cast<const float4*>(p + 4);
            }
        } else {
            #pragma unroll
            for (int i = 0; i < 4; ++i) {
                int u = i * 256 + t;
                int row = u >> 3, cb = (u & 7) * 16;
                ua[i] = *reinterpret_cast<const uint4*>(Arow + row * 512 + kk * 128 + cb);
            }
        }
    };
    auto writeA = [&]() {
        if (MODE == 0) {
            const int r = t >> 1;
            const int swzr = (r & 7) << 4;
            #pragma unroll
            for (int s = 0; s < 4; ++s) {
                uint4 pk = { pack2(fa[s][0].x, fa[s][0].y), pack2(fa[s][0].z, fa[s][0].w),
                             pack2(fa[s][1].x, fa[s][1].y), pack2(fa[s][1].z, fa[s][1].w) };
                int cb = (t & 1) * 64 + s * 16;
                *reinterpret_cast<uint4*>(AsB + r * 128 + (cb ^ swzr)) = pk;
            }
        } else {
            #pragma unroll
            for (int i = 0; i < 4; ++i) {
                int u = i * 256 + t;
                int row = u >> 3, cb = (u & 7) * 16;
                *reinterpret_cast<uint4*>(AsB + row * 128 + cb) = ua[i];
            }
        }
    };
    auto stageB = [&](int kk) {
        char* dst = BsB0 + (kk & 1) * 16384;
        #pragma unroll
        for (int i = 0; i < 4; ++i) {
            int u = (i * 4 + w) * 64 + lane;          // 1024 16B units
            int row = u >> 3, cb = (u & 7) * 16;
            gl_lds16(Bg + row * 512 + kk * 128 + cb, dst + (i * 4 + w) * 1024);
        }
    };

    f32x4 acc[4][4] = {};

    loadA(0);
    stageB(0);

    for (int kk = 0; kk < 4; ++kk) {
        writeA();
        __syncthreads();                 // A visible; B(kk) glds drained here
        if (kk < 3) { loadA(kk + 1); stageB(kk + 1); }   // fly during compute
        const char* Bcur = BsB0 + (kk & 1) * 16384;
        #pragma unroll
        for (int kc = 0; kc < 2; ++kc) {
            s16x8 af[4], bf[4];
            #pragma unroll
            for (int fm = 0; fm < 4; ++fm) {
                int r = wm * 64 + fm * 16 + lr;
                af[fm] = *reinterpret_cast<const s16x8*>(
                    AsB + r * 128 + ((kc * 64 + lk * 16) ^ ((r & 7) << 4)));
            }
            #pragma unroll
            for (int fn = 0; fn < 4; ++fn) {
                int cc = wn * 64 + fn * 16 + lr;
                bf[fn] = *reinterpret_cast<const s16x8*>(
                    Bcur + cc * 128 + ((kc * 64 + lk * 16) ^ ((cc & 7) << 4)));
            }
            __builtin_amdgcn_s_setprio(1);
            #pragma unroll
            for (int fm = 0; fm < 4; ++fm)
                #pragma unroll
                for (int fn = 0; fn < 4; ++fn)
                    acc[fm][fn] = __builtin_amdgcn_mfma_f32_16x16x32_bf16(af[fm], bf[fn], acc[fm][fn], 0, 0, 0);
            __builtin_amdgcn_s_setprio(0);
        }
        if (kk < 3) __syncthreads();     // reads done before next writeA
    }

    if (MODE == 1) {
        #pragma unroll
        for (int fn = 0; fn < 4; ++fn) {
            int colg = bn * 128 + wn * 64 + fn * 16 + lr;
            float bv = bias[colg];
            #pragma unroll
            for (int fm = 0; fm < 4; ++fm)
                #pragma unroll
                for (int j = 0; j < 4; ++j) {
                    int rg = bm * 128 + wm * 64 + fm * 16 + lk * 4 + j;
                    int n = rg >> 8, c = rg & 255;
                    int b = n >> 8, p = n & 255;
                    Out[(((b * 256 + c) * 256 + p) << 8) + colg] = acc[fm][fn][j] + bv;
                }
        }
        return;
    }

    // ---- MODE 0 epilogue: transpose through LDS (T overlaps As+Bs[0];
    // Bs[1] was the kk=3 read buffer -> barrier first).
    __syncthreads();
    unsigned short* T = (unsigned short*)smem;
    const int X = bn >> 1;            // 0=Q, 1=K, 2=V
    const int h0 = (bn & 1) * 2;
    const int n = bm >> 1;

    #pragma unroll
    for (int fn = 0; fn < 4; ++fn) {
        int col_local = wn * 64 + fn * 16 + lr;       // 0..127
        float bv = bias[bn * 128 + col_local];
        #pragma unroll
        for (int fm = 0; fm < 4; ++fm)
            #pragma unroll
            for (int j = 0; j < 4; ++j) {
                int c_local = wm * 64 + fm * 16 + lk * 4 + j;   // 0..127
                unsigned short hv = f2bf(acc[fm][fn][j] + bv);
                if (X < 2) {
                    *reinterpret_cast<unsigned short*>(
                        (char*)T + c_local * 256 + col_local * 2) = hv;
                } else {
                    int hl = col_local >> 6, d = col_local & 63;
                    *reinterpret_cast<unsigned short*>(
                        (char*)T + hl * 16384 + d * 256 + ((c_local * 2) ^ ((d & 7) << 4))) = hv;
                }
            }
    }
    __syncthreads();

    if (X < 2) {
        unsigned short* base = (X == 0) ? Qo : Ko;
        #pragma unroll
        for (int i = 0; i < 8; ++i) {
            int u = i * 256 + t;                 // 16B units, 2048 total
            int c_local = u >> 4;
            int cbyte = (u & 15) * 16;           // 0..255 across 2 heads
            int h = h0 + (cbyte >> 7);
            int db = cbyte & 127;
            uint4 vv = *reinterpret_cast<const uint4*>((char*)T + u * 16);
            int c = (bm & 1) * 128 + c_local;
            *reinterpret_cast<uint4*>(
                (char*)base + (size_t)((n * 4 + h) * 256 + c) * 128 + db) = vv;
        }
    } else {
        #pragma unroll
        for (int i = 0; i < 8; ++i) {
            int u = i * 256 + t;
            int rowr = u >> 4;                   // 0..127 (2 heads x 64 d)
            int hl = rowr >> 6, d = rowr & 63;
            int cb2 = (u & 15) * 16;
            int c2 = cb2 ^ ((d & 7) << 4);       // un-swizzle -> logical c byte
            uint4 vv = *reinterpret_cast<const uint4*>((char*)T + u * 16);
            *reinterpret_cast<uint4*>(
                (char*)Vt + (size_t)((n * 4 + h0 + hl) * 64 + d) * 512 + (bm & 1) * 256 + c2) = vv;
        }
    }
}

// ---------------------------------------------------------------------------
// Attention v6 (unchanged from round 5 — it works). One 512-thread block per
// (n,h); K+V in LDS (XOR-swizzled); in-register softmax; pack-early.
// ---------------------------------------------------------------------------
__global__ __launch_bounds__(512) VGPR_CAP_128 void attn6(
    const unsigned short* __restrict__ Q,
    const unsigned short* __restrict__ K,
    const unsigned short* __restrict__ V,
    unsigned short* __restrict__ O)
{
    __shared__ __align__(16) char KsB[32768];     // [256 key][128B] swizzled
    __shared__ __align__(16) char VsB[32768];     // [64 d][512B] swizzled
    __shared__ __align__(16) char OtrB[8][2048];  // per-wave transpose

    const int nh = blockIdx.x;
    const int n = nh >> 2, h = nh & 3;
    const int t = threadIdx.x, w = t >> 6, lane = t & 63;
    const int lr = lane & 15, lk = lane >> 4;

    const unsigned short* Qg = Q + (size_t)nh * 16384;
    const char* Kg = (const char*)K + (size_t)nh * 32768;
    const char* Vg = (const char*)V + (size_t)nh * 32768;

    #pragma unroll
    for (int i = 0; i < 4; ++i) {                 // stage K (2048 16B units)
        int u = i * 512 + t;
        int row = u >> 3, cb = (u & 7) * 16;
        uint4 val = *reinterpret_cast<const uint4*>(Kg + u * 16);
        *reinterpret_cast<uint4*>(KsB + row * 128 + (cb ^ ((row & 7) << 4))) = val;
    }
    #pragma unroll
    for (int i = 0; i < 4; ++i) {                 // stage V
        int u = i * 512 + t;
        int row = u >> 5, cb = (u & 31) * 16;
        uint4 val = *reinterpret_cast<const uint4*>(Vg + u * 16);
        *reinterpret_cast<uint4*>(VsB + row * 512 + (cb ^ ((row & 7) << 4))) = val;
    }
    __syncthreads();

    const float sc = 0.125f * 1.44269504f;   // HD^-0.5 * log2(e)
    const int swz = (lr & 7) << 4;

    #pragma unroll
    for (int it = 0; it < 2; ++it) {
        const int qt = w * 2 + it;

        s16x8 bq0 = *reinterpret_cast<const s16x8*>(Qg + (qt * 16 + lr) * 64 + lk * 8);
        s16x8 bq1 = *reinterpret_cast<const s16x8*>(Qg + (qt * 16 + lr) * 64 + 32 + lk * 8);

        // S^T: lane holds S[key = 16*kt + 4*lk + j][q = qt*16+lr]
        f32x4 s[16];
        #pragma unroll
        for (int kt = 0; kt < 16; ++kt) {
            const int rb = (kt * 16 + lr) * 128;
            s16x8 a0 = *reinterpret_cast<const s16x8*>(KsB + rb + ((lk * 16) ^ swz));
            s16x8 a1 = *reinterpret_cast<const s16x8*>(KsB + rb + ((64 + lk * 16) ^ swz));
            f32x4 z = { 0.f, 0.f, 0.f, 0.f };
            __builtin_amdgcn_s_setprio(1);
            z = __builtin_amdgcn_mfma_f32_16x16x32_bf16(a0, bq0, z, 0, 0, 0);
            z = __builtin_amdgcn_mfma_f32_16x16x32_bf16(a1, bq1, z, 0, 0, 0);
            __builtin_amdgcn_s_setprio(0);
            s[kt] = z;
        }

        // tree max over 256 keys
        float m8[8];
        #pragma unroll
        for (int i = 0; i < 8; ++i) {
            float a = fmaxf(fmaxf(s[i][0], s[i][1]), fmaxf(s[i][2], s[i][3]));
            float b = fmaxf(fmaxf(s[i + 8][0], s[i + 8][1]), fmaxf(s[i + 8][2], s[i + 8][3]));
            m8[i] = fmaxf(a, b);
        }
        float m = fmaxf(fmaxf(fmaxf(m8[0], m8[1]), fmaxf(m8[2], m8[3])),
                        fmaxf(fmaxf(m8[4], m8[5]), fmaxf(m8[6], m8[7])));
        m = fmaxf(m, __shfl_xor(m, 16));
        m = fmaxf(m, __shfl_xor(m, 32));

        // exp fused with pack: s[] dies into pf[] (permuted-key bijection)
        const float nb = -m * sc;
        float lp[8];
        s16x8 pf[8];
        #pragma unroll
        for (int kb = 0; kb < 8; ++kb) {
            float p0 = exp2f(__builtin_fmaf(s[2 * kb][0], sc, nb));
            float p1 = exp2f(__builtin_fmaf(s[2 * kb][1], sc, nb));
            float p2 = exp2f(__builtin_fmaf(s[2 * kb][2], sc, nb));
            float p3 = exp2f(__builtin_fmaf(s[2 * kb][3], sc, nb));
            float p4 = exp2f(__builtin_fmaf(s[2 * kb + 1][0], sc, nb));
            float p5 = exp2f(__builtin_fmaf(s[2 * kb + 1][1], sc, nb));
            float p6 = exp2f(__builtin_fmaf(s[2 * kb + 1][2], sc, nb));
            float p7 = exp2f(__builtin_fmaf(s[2 * kb + 1][3], sc, nb));
            lp[kb] = ((p0 + p1) + (p2 + p3)) + ((p4 + p5) + (p6 + p7));
            uint4 pk = { pack2(p0, p1), pack2(p2, p3), pack2(p4, p5), pack2(p6, p7) };
            pf[kb] = u4cast(pk);
        }
        float l = ((lp[0] + lp[1]) + (lp[2] + lp[3])) + ((lp[4] + lp[5]) + (lp[6] + lp[7]));
        l += __shfl_xor(l, 16);
        l += __shfl_xor(l, 32);

        // O^T = V^T @ P^T, V from LDS (swizzled), permuted-key bijection
        f32x4 oacc[4] = {};
        #pragma unroll
        for (int kb = 0; kb < 8; ++kb) {
            #pragma unroll
            for (int dt = 0; dt < 4; ++dt) {
                const char* vb = VsB + (dt * 16 + lr) * 512;
                uint2 v0 = *reinterpret_cast<const uint2*>(vb + ((kb * 64 + lk * 8) ^ swz));
                uint2 v1 = *reinterpret_cast<const uint2*>(vb + ((kb * 64 + lk * 8 + 32) ^ swz));
                uint4 uu = { v0.x, v0.y, v1.x, v1.y };
                __builtin_amdgcn_s_setprio(1);
                oacc[dt] = __builtin_amdgcn_mfma_f32_16x16x32_bf16(u4cast(uu), pf[kb], oacc[dt], 0, 0, 0);
                __builtin_amdgcn_s_setprio(0);
            }
        }

        // normalize; transpose via per-wave LDS; store PRE-SWIZZLED for gemm2
        const float rl = 1.0f / l;
        char* ob = OtrB[w];
        #pragma unroll
        for (int dt = 0; dt < 4; ++dt) {
            unsigned int w0 = pack2(oacc[dt][0] * rl, oacc[dt][1] * rl);
            unsigned int w1 = pack2(oacc[dt][2] * rl, oacc[dt][3] * rl);
            int cb0 = dt * 32 + lk * 8;
            *reinterpret_cast<unsigned int*>(ob + lr * 128 + (cb0 ^ swz)) = w0;
            *reinterpret_cast<unsigned int*>(ob + lr * 128 + ((cb0 + 4) ^ swz)) = w1;
        }
        #pragma unroll
        for (int pp = 0; pp < 2; ++pp) {
            int qrow = lane >> 2;
            int cbX = (lane & 3) * 32 + pp * 16;   // PHYS offset (swizzles cancel)
            uint4 vv = *reinterpret_cast<const uint4*>(ob + qrow * 128 + cbX);
            *reinterpret_cast<uint4*>(
                (char*)O + (size_t)(n * 256 + qt * 16 + qrow) * 512 + h * 128 + cbX) = vv;
        }
    }
}

// ---------------------------------------------------------------------------
extern "C" void kernel_launch(void* const* d_in, const int* in_sizes, int n_in,
                              void* d_out, int out_size, void* d_ws, size_t ws_size,
                              hipStream_t stream) {
    const float* x     = (const float*)d_in[0];
    const float* w_in  = (const float*)d_in[1];
    const float* b_in  = (const float*)d_in[2];
    const float* w_out = (const float*)d_in[3];
    const float* b_out = (const float*)d_in[4];

    char* ws = (char*)d_ws;
    unsigned short* tO = (unsigned short*)(ws);               // O
    unsigned short* Qw = (unsigned short*)(ws + WS_SEG);
    unsigned short* Kw = (unsigned short*)(ws + 2 * WS_SEG);
    unsigned short* Vw = (unsigned short*)(ws + 3 * WS_SEG);

    // bf16 w_in in d_out tail (read by gemm1, overwritten later by gemm2)
    unsigned short* WbIn = (unsigned short*)((float*)d_out + out_size - 98304);

    convw_swz<<<192, 256, 0, stream>>>(w_in, WbIn);

    // gemm1 with FUSED patch-gather (no standalone gather kernel)
    gemm4<0><<<6144, 256, 0, stream>>>(x, nullptr, WbIn, b_in,
                                       Qw, Kw, Vw, nullptr);

    attn6<<<2048, 512, 0, stream>>>(Qw, Kw, Vw, tO);

    unsigned short* WbOut = Kw;                               // K dead after attn
    convw_swz<<<64, 256, 0, stream>>>(w_out, WbOut);

    gemm4<1><<<2048, 256, 0, stream>>>(nullptr, tO, WbOut, b_out,
                                       nullptr, nullptr, nullptr, (float*)d_out);
}

// Round 7
// 290.224 us; speedup vs baseline: 1.2893x; 1.2893x over previous
//
#include <hip/hip_runtime.h>
#include <hip/hip_bf16.h>

typedef __attribute__((ext_vector_type(8))) short s16x8;
typedef __attribute__((ext_vector_type(4))) float f32x4;

#define WS_SEG 67108864ULL  // 64 MiB regions: [t/O][Q][K][Vt]

#if defined(__has_attribute)
#if __has_attribute(amdgpu_num_vgpr)
#define VGPR_CAP_128 __attribute__((amdgpu_num_vgpr(128)))
#else
#define VGPR_CAP_128
#endif
#else
#define VGPR_CAP_128
#endif

static __device__ __forceinline__ unsigned short f2bf(float f) {
    return __builtin_bit_cast(unsigned short, __float2bfloat16(f));   // RNE v_cvt
}
static __device__ __forceinline__ unsigned int pack2(float a, float b) {
    return (unsigned int)f2bf(a) | ((unsigned int)f2bf(b) << 16);     // v_cvt_pk path
}
static __device__ __forceinline__ s16x8 u4cast(uint4 u) {
    return __builtin_bit_cast(s16x8, u);
}
// async global->LDS, 16B per lane; lds dest = wave-uniform base + lane*16
static __device__ __forceinline__ void gl_lds16(const void* g, void* l) {
    __builtin_amdgcn_global_load_lds(
        (const __attribute__((address_space(1))) unsigned int*)g,
        (__attribute__((address_space(3))) unsigned int*)l, 16, 0, 0);
}

// ---------------------------------------------------------------------------
// Weight convert f32 -> bf16, pre-swizzled: within each 128B k-chunk of a row,
// phys_cb = cb ^ ((row&7)<<4).
// ---------------------------------------------------------------------------
__global__ __launch_bounds__(256) void convw_swz(const float* __restrict__ wi,
                                                 unsigned short* __restrict__ wb) {
    int i = (blockIdx.x * 256 + threadIdx.x) * 4;   // element idx
    float4 v = *reinterpret_cast<const float4*>(wi + i);
    int bb = i * 2;                                  // byte addr in bf16 matrix
    int row = i >> 8;
    int dst = (bb & ~127) | ((bb & 127) ^ ((row & 7) << 4));
    uint2 o = { pack2(v.x, v.y), pack2(v.z, v.w) };
    *reinterpret_cast<uint2*>((char*)wb + dst) = o;
}

// ---------------------------------------------------------------------------
// Patch gather x[2,256,256,256] f32 -> t bf16 [131072][256], pre-swizzled.
// (Round-5 verified; re-instated after the round-6 fusion regression.)
// ---------------------------------------------------------------------------
__global__ __launch_bounds__(256) void gather_swz(const float* __restrict__ x,
                                                  unsigned short* __restrict__ t) {
    int q = (blockIdx.x * 256 + threadIdx.x) * 4;
    int e = q & 255, c = (q >> 8) & 255, n = q >> 16;
    int b = n >> 8, p = n & 255;
    int xi = ((b * 256 + c) * 256 + (p >> 4) * 16 + (e >> 4)) * 256 + (p & 15) * 16 + (e & 15);
    float4 v = *reinterpret_cast<const float4*>(x + xi);
    int bb = q * 2;
    int row = q >> 8;
    int dst = (bb & ~127) | ((bb & 127) ^ ((row & 7) << 4));
    uint2 o = { pack2(v.x, v.y), pack2(v.z, v.w) };
    *reinterpret_cast<uint2*>((char*)t + dst) = o;
}

// ---------------------------------------------------------------------------
// GEMM v5: C[M=131072][N] = A @ W^T + bias. A,W bf16 [*][256] PRE-SWIZZLED
// (within-128B XOR keyed by row&7). Tile 128x128, BK=128 -> only TWO K-tiles
// and 4 barriers per block (was 8). LDS 64KB single-buffered (A 32K + B 32K)
// -> 2 blocks/CU; the co-resident block's 64-MFMA compute phase hides this
// block's stage drain. 4 waves (2x2), each 64x64 out.
// A-source: t (MODE 0) or attn-O (MODE 1) — identical layout, shared path.
// 1-D grid, XCD-chunked: NB consecutive bn per bm -> A re-reads are L2-hits.
// MODE 0 epilogue: LDS transpose -> Q/K [nh][c][64], Vt [nh][64][c].
// MODE 1 epilogue: direct f32 stores to out [b][c][p][e].
// ---------------------------------------------------------------------------
template<int MODE>
__global__ __launch_bounds__(256) void gemm5(
    const unsigned short* __restrict__ Ab,
    const unsigned short* __restrict__ Wb,
    const float* __restrict__ bias,
    unsigned short* __restrict__ Qo, unsigned short* __restrict__ Ko,
    unsigned short* __restrict__ Vt, float* __restrict__ Out)
{
    __shared__ __align__(16) char smem[65536];   // As 32K | Bs 32K
    char* AsB = smem;
    char* BsB = smem + 32768;

    const int t = threadIdx.x, w = t >> 6, lane = t & 63;
    const int lr = lane & 15, lk = lane >> 4;
    const int wm = w >> 1, wn = w & 1;

    constexpr int NB = (MODE == 0) ? 6 : 2;
    const int flat = blockIdx.x;
    const int xcd = flat & 7, idx = flat >> 3;
    const int bm = xcd * ((MODE == 0) ? 128 : 128) + idx / NB;
    const int bn = idx % NB;

    const char* Ag = (const char*)Ab + (size_t)bm * 65536;   // 128 rows * 512B
    const char* Bg = (const char*)Wb + (size_t)bn * 65536;

    f32x4 acc[4][4] = {};

    for (int kk = 0; kk < 2; ++kk) {
        // stage A-half and B-half (32KB each): 8 x 16B units per thread each
        #pragma unroll
        for (int i = 0; i < 8; ++i) {
            int u = i * 256 + t;                 // 0..2047 16B units
            int row = u >> 4, cb = (u & 15) * 16;
            gl_lds16(Ag + row * 512 + kk * 256 + cb, AsB + (i * 256 + w * 64) * 16);
            gl_lds16(Bg + row * 512 + kk * 256 + cb, BsB + (i * 256 + w * 64) * 16);
        }
        __syncthreads();                          // drain glds; LDS visible
        #pragma unroll
        for (int kc = 0; kc < 4; ++kc) {
            const int kcol = (kc & 1) * 64 + lk * 16;   // within-128B part
            const int khi = (kc >> 1) * 128;            // which 128B half
            s16x8 af[4], bf[4];
            #pragma unroll
            for (int fm = 0; fm < 4; ++fm) {
                int r = wm * 64 + fm * 16 + lr;
                af[fm] = *reinterpret_cast<const s16x8*>(
                    AsB + r * 256 + khi + (kcol ^ ((r & 7) << 4)));
            }
            #pragma unroll
            for (int fn = 0; fn < 4; ++fn) {
                int cc = wn * 64 + fn * 16 + lr;
                bf[fn] = *reinterpret_cast<const s16x8*>(
                    BsB + cc * 256 + khi + (kcol ^ ((cc & 7) << 4)));
            }
            #pragma unroll
            for (int fm = 0; fm < 4; ++fm)
                #pragma unroll
                for (int fn = 0; fn < 4; ++fn)
                    acc[fm][fn] = __builtin_amdgcn_mfma_f32_16x16x32_bf16(af[fm], bf[fn], acc[fm][fn], 0, 0, 0);
        }
        __syncthreads();                          // reads done before overwrite
    }

    if (MODE == 1) {
        #pragma unroll
        for (int fn = 0; fn < 4; ++fn) {
            int colg = bn * 128 + wn * 64 + fn * 16 + lr;
            float bv = bias[colg];
            #pragma unroll
            for (int fm = 0; fm < 4; ++fm)
                #pragma unroll
                for (int j = 0; j < 4; ++j) {
                    int rg = bm * 128 + wm * 64 + fm * 16 + lk * 4 + j;
                    int n = rg >> 8, c = rg & 255;
                    int b = n >> 8, p = n & 255;
                    Out[(((b * 256 + c) * 256 + p) << 8) + colg] = acc[fm][fn][j] + bv;
                }
        }
        return;
    }

    // ---- MODE 0 epilogue: transpose through LDS (smem dead after barrier).
    unsigned short* T = (unsigned short*)smem;
    const int X = bn >> 1;            // 0=Q, 1=K, 2=V
    const int h0 = (bn & 1) * 2;
    const int n = bm >> 1;

    #pragma unroll
    for (int fn = 0; fn < 4; ++fn) {
        int col_local = wn * 64 + fn * 16 + lr;       // 0..127
        float bv = bias[bn * 128 + col_local];
        #pragma unroll
        for (int fm = 0; fm < 4; ++fm)
            #pragma unroll
            for (int j = 0; j < 4; ++j) {
                int c_local = wm * 64 + fm * 16 + lk * 4 + j;   // 0..127
                unsigned short hv = f2bf(acc[fm][fn][j] + bv);
                if (X < 2) {
                    *reinterpret_cast<unsigned short*>(
                        (char*)T + c_local * 256 + col_local * 2) = hv;
                } else {
                    int hl = col_local >> 6, d = col_local & 63;
                    *reinterpret_cast<unsigned short*>(
                        (char*)T + hl * 16384 + d * 256 + ((c_local * 2) ^ ((d & 7) << 4))) = hv;
                }
            }
    }
    __syncthreads();

    if (X < 2) {
        unsigned short* base = (X == 0) ? Qo : Ko;
        #pragma unroll
        for (int i = 0; i < 8; ++i) {
            int u = i * 256 + t;                 // 16B units, 2048 total
            int c_local = u >> 4;
            int cbyte = (u & 15) * 16;           // 0..255 across 2 heads
            int h = h0 + (cbyte >> 7);
            int db = cbyte & 127;
            uint4 vv = *reinterpret_cast<const uint4*>((char*)T + u * 16);
            int c = (bm & 1) * 128 + c_local;
            *reinterpret_cast<uint4*>(
                (char*)base + (size_t)((n * 4 + h) * 256 + c) * 128 + db) = vv;
        }
    } else {
        #pragma unroll
        for (int i = 0; i < 8; ++i) {
            int u = i * 256 + t;
            int rowr = u >> 4;                   // 0..127 (2 heads x 64 d)
            int hl = rowr >> 6, d = rowr & 63;
            int cb2 = (u & 15) * 16;
            int c2 = cb2 ^ ((d & 7) << 4);       // un-swizzle -> logical c byte
            uint4 vv = *reinterpret_cast<const uint4*>((char*)T + u * 16);
            *reinterpret_cast<uint4*>(
                (char*)Vt + (size_t)((n * 4 + h0 + hl) * 64 + d) * 512 + (bm & 1) * 256 + c2) = vv;
        }
    }
}

// ---------------------------------------------------------------------------
// Attention v6 (unchanged — round-5 verified). One 512-thread block per
// (n,h); K+V in LDS (XOR-swizzled); in-register softmax; pack-early.
// ---------------------------------------------------------------------------
__global__ __launch_bounds__(512) VGPR_CAP_128 void attn6(
    const unsigned short* __restrict__ Q,
    const unsigned short* __restrict__ K,
    const unsigned short* __restrict__ V,
    unsigned short* __restrict__ O)
{
    __shared__ __align__(16) char KsB[32768];     // [256 key][128B] swizzled
    __shared__ __align__(16) char VsB[32768];     // [64 d][512B] swizzled
    __shared__ __align__(16) char OtrB[8][2048];  // per-wave transpose

    const int nh = blockIdx.x;
    const int n = nh >> 2, h = nh & 3;
    const int t = threadIdx.x, w = t >> 6, lane = t & 63;
    const int lr = lane & 15, lk = lane >> 4;

    const unsigned short* Qg = Q + (size_t)nh * 16384;
    const char* Kg = (const char*)K + (size_t)nh * 32768;
    const char* Vg = (const char*)V + (size_t)nh * 32768;

    #pragma unroll
    for (int i = 0; i < 4; ++i) {                 // stage K (2048 16B units)
        int u = i * 512 + t;
        int row = u >> 3, cb = (u & 7) * 16;
        uint4 val = *reinterpret_cast<const uint4*>(Kg + u * 16);
        *reinterpret_cast<uint4*>(KsB + row * 128 + (cb ^ ((row & 7) << 4))) = val;
    }
    #pragma unroll
    for (int i = 0; i < 4; ++i) {                 // stage V
        int u = i * 512 + t;
        int row = u >> 5, cb = (u & 31) * 16;
        uint4 val = *reinterpret_cast<const uint4*>(Vg + u * 16);
        *reinterpret_cast<uint4*>(VsB + row * 512 + (cb ^ ((row & 7) << 4))) = val;
    }
    __syncthreads();

    const float sc = 0.125f * 1.44269504f;   // HD^-0.5 * log2(e)
    const int swz = (lr & 7) << 4;

    #pragma unroll
    for (int it = 0; it < 2; ++it) {
        const int qt = w * 2 + it;

        s16x8 bq0 = *reinterpret_cast<const s16x8*>(Qg + (qt * 16 + lr) * 64 + lk * 8);
        s16x8 bq1 = *reinterpret_cast<const s16x8*>(Qg + (qt * 16 + lr) * 64 + 32 + lk * 8);

        // S^T: lane holds S[key = 16*kt + 4*lk + j][q = qt*16+lr]
        f32x4 s[16];
        #pragma unroll
        for (int kt = 0; kt < 16; ++kt) {
            const int rb = (kt * 16 + lr) * 128;
            s16x8 a0 = *reinterpret_cast<const s16x8*>(KsB + rb + ((lk * 16) ^ swz));
            s16x8 a1 = *reinterpret_cast<const s16x8*>(KsB + rb + ((64 + lk * 16) ^ swz));
            f32x4 z = { 0.f, 0.f, 0.f, 0.f };
            __builtin_amdgcn_s_setprio(1);
            z = __builtin_amdgcn_mfma_f32_16x16x32_bf16(a0, bq0, z, 0, 0, 0);
            z = __builtin_amdgcn_mfma_f32_16x16x32_bf16(a1, bq1, z, 0, 0, 0);
            __builtin_amdgcn_s_setprio(0);
            s[kt] = z;
        }

        // tree max over 256 keys
        float m8[8];
        #pragma unroll
        for (int i = 0; i < 8; ++i) {
            float a = fmaxf(fmaxf(s[i][0], s[i][1]), fmaxf(s[i][2], s[i][3]));
            float b = fmaxf(fmaxf(s[i + 8][0], s[i + 8][1]), fmaxf(s[i + 8][2], s[i + 8][3]));
            m8[i] = fmaxf(a, b);
        }
        float m = fmaxf(fmaxf(fmaxf(m8[0], m8[1]), fmaxf(m8[2], m8[3])),
                        fmaxf(fmaxf(m8[4], m8[5]), fmaxf(m8[6], m8[7])));
        m = fmaxf(m, __shfl_xor(m, 16));
        m = fmaxf(m, __shfl_xor(m, 32));

        // exp fused with pack: s[] dies into pf[] (permuted-key bijection)
        const float nb = -m * sc;
        float lp[8];
        s16x8 pf[8];
        #pragma unroll
        for (int kb = 0; kb < 8; ++kb) {
            float p0 = exp2f(__builtin_fmaf(s[2 * kb][0], sc, nb));
            float p1 = exp2f(__builtin_fmaf(s[2 * kb][1], sc, nb));
            float p2 = exp2f(__builtin_fmaf(s[2 * kb][2], sc, nb));
            float p3 = exp2f(__builtin_fmaf(s[2 * kb][3], sc, nb));
            float p4 = exp2f(__builtin_fmaf(s[2 * kb + 1][0], sc, nb));
            float p5 = exp2f(__builtin_fmaf(s[2 * kb + 1][1], sc, nb));
            float p6 = exp2f(__builtin_fmaf(s[2 * kb + 1][2], sc, nb));
            float p7 = exp2f(__builtin_fmaf(s[2 * kb + 1][3], sc, nb));
            lp[kb] = ((p0 + p1) + (p2 + p3)) + ((p4 + p5) + (p6 + p7));
            uint4 pk = { pack2(p0, p1), pack2(p2, p3), pack2(p4, p5), pack2(p6, p7) };
            pf[kb] = u4cast(pk);
        }
        float l = ((lp[0] + lp[1]) + (lp[2] + lp[3])) + ((lp[4] + lp[5]) + (lp[6] + lp[7]));
        l += __shfl_xor(l, 16);
        l += __shfl_xor(l, 32);

        // O^T = V^T @ P^T, V from LDS (swizzled), permuted-key bijection
        f32x4 oacc[4] = {};
        #pragma unroll
        for (int kb = 0; kb < 8; ++kb) {
            #pragma unroll
            for (int dt = 0; dt < 4; ++dt) {
                const char* vb = VsB + (dt * 16 + lr) * 512;
                uint2 v0 = *reinterpret_cast<const uint2*>(vb + ((kb * 64 + lk * 8) ^ swz));
                uint2 v1 = *reinterpret_cast<const uint2*>(vb + ((kb * 64 + lk * 8 + 32) ^ swz));
                uint4 uu = { v0.x, v0.y, v1.x, v1.y };
                __builtin_amdgcn_s_setprio(1);
                oacc[dt] = __builtin_amdgcn_mfma_f32_16x16x32_bf16(u4cast(uu), pf[kb], oacc[dt], 0, 0, 0);
                __builtin_amdgcn_s_setprio(0);
            }
        }

        // normalize; transpose via per-wave LDS; store PRE-SWIZZLED for gemm2
        const float rl = 1.0f / l;
        char* ob = OtrB[w];
        #pragma unroll
        for (int dt = 0; dt < 4; ++dt) {
            unsigned int w0 = pack2(oacc[dt][0] * rl, oacc[dt][1] * rl);
            unsigned int w1 = pack2(oacc[dt][2] * rl, oacc[dt][3] * rl);
            int cb0 = dt * 32 + lk * 8;
            *reinterpret_cast<unsigned int*>(ob + lr * 128 + (cb0 ^ swz)) = w0;
            *reinterpret_cast<unsigned int*>(ob + lr * 128 + ((cb0 + 4) ^ swz)) = w1;
        }
        #pragma unroll
        for (int pp = 0; pp < 2; ++pp) {
            int qrow = lane >> 2;
            int cbX = (lane & 3) * 32 + pp * 16;   // PHYS offset (swizzles cancel)
            uint4 vv = *reinterpret_cast<const uint4*>(ob + qrow * 128 + cbX);
            *reinterpret_cast<uint4*>(
                (char*)O + (size_t)(n * 256 + qt * 16 + qrow) * 512 + h * 128 + cbX) = vv;
        }
    }
}

// ---------------------------------------------------------------------------
extern "C" void kernel_launch(void* const* d_in, const int* in_sizes, int n_in,
                              void* d_out, int out_size, void* d_ws, size_t ws_size,
                              hipStream_t stream) {
    const float* x     = (const float*)d_in[0];
    const float* w_in  = (const float*)d_in[1];
    const float* b_in  = (const float*)d_in[2];
    const float* w_out = (const float*)d_in[3];
    const float* b_out = (const float*)d_in[4];

    char* ws = (char*)d_ws;
    unsigned short* tO = (unsigned short*)(ws);               // t, later O
    unsigned short* Qw = (unsigned short*)(ws + WS_SEG);
    unsigned short* Kw = (unsigned short*)(ws + 2 * WS_SEG);
    unsigned short* Vw = (unsigned short*)(ws + 3 * WS_SEG);

    // bf16 w_in in d_out tail (read by gemm1, overwritten later by gemm2)
    unsigned short* WbIn = (unsigned short*)((float*)d_out + out_size - 98304);

    convw_swz<<<192, 256, 0, stream>>>(w_in, WbIn);
    gather_swz<<<32768, 256, 0, stream>>>(x, tO);

    gemm5<0><<<6144, 256, 0, stream>>>(tO, WbIn, b_in, Qw, Kw, Vw, nullptr);

    attn6<<<2048, 512, 0, stream>>>(Qw, Kw, Vw, tO);          // O overwrites t

    unsigned short* WbOut = Kw;                               // K dead after attn
    convw_swz<<<64, 256, 0, stream>>>(w_out, WbOut);

    gemm5<1><<<2048, 256, 0, stream>>>(tO, WbOut, b_out,
                                       nullptr, nullptr, nullptr, (float*)d_out);
}